// Round 1
// baseline (493.985 us; speedup 1.0000x reference)
//
#include <hip/hip_runtime.h>
#include <hip/hip_bf16.h>
#include <math.h>

#define Bb 16
#define Cc 512
#define Nn 2048

typedef unsigned short u16;
typedef __attribute__((ext_vector_type(8))) short bf16x8;
typedef __attribute__((ext_vector_type(4))) float f32x4;

__device__ __forceinline__ float b2f(u16 u){ unsigned x = ((unsigned)u) << 16; return __builtin_bit_cast(float, x); }
__device__ __forceinline__ u16 f2b(float f){
  unsigned x = __builtin_bit_cast(unsigned, f);
  x += 0x7fffu + ((x >> 16) & 1u);
  return (u16)(x >> 16);
}

// ---------------- GroupNorm -> h (bf16) ----------------
// one block per (batch, group); group = 16 consecutive channels * 2048 = 32768 contiguous floats
__global__ __launch_bounds__(256) void k_gn(const float* __restrict__ x,
                                            const float* __restrict__ gamma,
                                            const float* __restrict__ beta,
                                            u16* __restrict__ h){
  int bid = blockIdx.x;
  int b = bid >> 5, g = bid & 31;
  const float4* xv = (const float4*)(x + ((size_t)b * Cc + g * 16) * Nn);
  u16* hp = h + ((size_t)b * Cc + g * 16) * Nn;
  int t = threadIdx.x;
  float s = 0.f, ss = 0.f;
#pragma unroll 4
  for (int it = 0; it < 32; ++it){
    float4 v = xv[it * 256 + t];
    s  += v.x + v.y + v.z + v.w;
    ss += v.x * v.x + v.y * v.y + v.z * v.z + v.w * v.w;
  }
#pragma unroll
  for (int o = 32; o >= 1; o >>= 1){ s += __shfl_xor(s, o); ss += __shfl_xor(ss, o); }
  __shared__ float rs[4], rss[4];
  int w = t >> 6;
  if ((t & 63) == 0){ rs[w] = s; rss[w] = ss; }
  __syncthreads();
  s  = rs[0] + rs[1] + rs[2] + rs[3];
  ss = rss[0] + rss[1] + rss[2] + rss[3];
  float mean = s * (1.f / 32768.f);
  float var  = ss * (1.f / 32768.f) - mean * mean;
  float inv  = rsqrtf(var + 1e-6f);
#pragma unroll 4
  for (int it = 0; it < 32; ++it){
    int idx = it * 256 + t;
    float4 u = xv[idx];
    int ch = g * 16 + (idx >> 9);   // (idx*4)/2048
    float ga = gamma[ch] * inv, be = beta[ch];
    ushort4 o;
    o.x = f2b((u.x - mean) * ga + be);
    o.y = f2b((u.y - mean) * ga + be);
    o.z = f2b((u.z - mean) * ga + be);
    o.w = f2b((u.w - mean) * ga + be);
    ((ushort4*)hp)[idx] = o;
  }
}

// ---------------- shared GEMM pieces ----------------
// LDS tiles: As[m][k], Bs[n][k] (B operand pre-transposed), 128 rows x 32 k, bf16.
// XOR swizzle: k' = k ^ ((row&3)<<3)  -> fragment b128 reads are <=4-way conflicted.
#define LDS_SZ (128 * 32)

__device__ __forceinline__ void stage_direct_bf16(u16* __restrict__ dst, const u16* __restrict__ src, int stride){
  int t = threadIdx.x;
#pragma unroll
  for (int it = 0; it < 2; ++it){
    int m  = it * 64 + (t >> 2);
    int k0 = (t & 3) << 3;
    uint4 vv = *(const uint4*)(src + (size_t)m * stride + k0);
    *(uint4*)(dst + m * 32 + (k0 ^ ((m & 3) << 3))) = vv;
  }
}

__device__ __forceinline__ void stage_direct_f32(u16* __restrict__ dst, const float* __restrict__ src, int stride){
  int t = threadIdx.x;
#pragma unroll
  for (int it = 0; it < 2; ++it){
    int m  = it * 64 + (t >> 2);
    int k0 = (t & 3) << 3;
    const float4* sp = (const float4*)(src + (size_t)m * stride + k0);
    float4 a = sp[0], b = sp[1];
    u16 tmp[8] = { f2b(a.x), f2b(a.y), f2b(a.z), f2b(a.w),
                   f2b(b.x), f2b(b.y), f2b(b.z), f2b(b.w) };
    *(uint4*)(dst + m * 32 + (k0 ^ ((m & 3) << 3))) = *(const uint4*)tmp;
  }
}

// dst[n][k] = src[k*stride + n]  (k in [0,32), n in [0,128))
// per-thread: gather 8 source rows at one column -> one contiguous 16B LDS write
__device__ __forceinline__ void stage_transpose(u16* __restrict__ dst, const u16* __restrict__ src, int stride){
  int t = threadIdx.x;
#pragma unroll
  for (int it = 0; it < 2; ++it){
    int id = it * 256 + t;
    int n  = id & 127;
    int kb = (id >> 7) << 3;    // 0,8,16,24
    u16 tmp[8];
#pragma unroll
    for (int e = 0; e < 8; ++e) tmp[e] = src[(size_t)(kb + e) * stride + n];
    *(uint4*)(dst + n * 32 + (kb ^ ((n & 3) << 3))) = *(const uint4*)tmp;
  }
}

__device__ __forceinline__ void gemm_step(const u16* __restrict__ As, const u16* __restrict__ Bs,
                                          f32x4 (&acc)[4][4], int wm, int wn, int lr, int sw){
  bf16x8 af[4], bf[4];
#pragma unroll
  for (int f = 0; f < 4; ++f) af[f] = *(const bf16x8*)&As[(wm + f * 16 + lr) * 32 + sw];
#pragma unroll
  for (int f = 0; f < 4; ++f) bf[f] = *(const bf16x8*)&Bs[(wn + f * 16 + lr) * 32 + sw];
#pragma unroll
  for (int i = 0; i < 4; ++i)
#pragma unroll
    for (int j = 0; j < 4; ++j)
      acc[i][j] = __builtin_amdgcn_mfma_f32_16x16x32_bf16(af[i], bf[j], acc[i][j], 0, 0, 0);
}

#define GEMM_PROLOGUE \
  int lane = threadIdx.x & 63, wid = threadIdx.x >> 6; \
  int wm = (wid >> 1) * 64, wn = (wid & 1) * 64; \
  int lr = lane & 15, lk = (lane >> 4) << 3; \
  int sw = lk ^ ((lr & 3) << 3); \
  f32x4 acc[4][4]; \
  { f32x4 z = {0.f, 0.f, 0.f, 0.f}; \
    for (int i = 0; i < 4; ++i) for (int j = 0; j < 4; ++j) acc[i][j] = z; }

// ---------------- QKV projections ----------------
__global__ __launch_bounds__(256) void k_qkv(const u16* __restrict__ h,
    const float* __restrict__ wq, const float* __restrict__ bq,
    const float* __restrict__ wk, const float* __restrict__ bk,
    const float* __restrict__ wv, const float* __restrict__ bv,
    u16* __restrict__ q, u16* __restrict__ k, u16* __restrict__ v){
  __shared__ u16 As[LDS_SZ], Bs[LDS_SZ];
  int z = blockIdx.z, b = z / 3, p = z - b * 3;
  const float* W  = (p == 0) ? wq : (p == 1) ? wk : wv;
  const float* bi = (p == 0) ? bq : (p == 1) ? bk : bv;
  u16* out = ((p == 0) ? q : (p == 1) ? k : v) + (size_t)b * Cc * Nn;
  const u16* hb = h + (size_t)b * Cc * Nn;
  int m0 = blockIdx.x * 128, n0 = blockIdx.y * 128;
  GEMM_PROLOGUE
  for (int k0 = 0; k0 < Cc; k0 += 32){
    stage_direct_f32(As, W + (size_t)m0 * Cc + k0, Cc);
    stage_transpose(Bs, hb + (size_t)k0 * Nn + n0, Nn);
    __syncthreads();
    gemm_step(As, Bs, acc, wm, wn, lr, sw);
    __syncthreads();
  }
  int r0 = m0 + wm + ((lane >> 4) << 2);
#pragma unroll
  for (int i = 0; i < 4; ++i)
#pragma unroll
    for (int j = 0; j < 4; ++j){
      int col = n0 + wn + j * 16 + lr;
#pragma unroll
      for (int r = 0; r < 4; ++r){
        int row = r0 + i * 16 + r;
        out[(size_t)row * Nn + col] = f2b(acc[i][j][r] + bi[row]);
      }
    }
}

// ---------------- scores: P = softmax-input = scale * Q^T K (bf16) ----------------
__global__ __launch_bounds__(256) void k_scores(const u16* __restrict__ q, const u16* __restrict__ kmat,
                                                u16* __restrict__ p){
  __shared__ u16 As[LDS_SZ], Bs[LDS_SZ];
  int b = blockIdx.z;
  const u16* qb = q + (size_t)b * Cc * Nn;
  const u16* kb = kmat + (size_t)b * Cc * Nn;
  u16* pb = p + (size_t)b * Nn * Nn;
  int m0 = blockIdx.x * 128, n0 = blockIdx.y * 128;
  GEMM_PROLOGUE
  for (int k0 = 0; k0 < Cc; k0 += 32){
    stage_transpose(As, qb + (size_t)k0 * Nn + m0, Nn);  // As[i][c] = q[c][i]
    stage_transpose(Bs, kb + (size_t)k0 * Nn + n0, Nn);  // Bs[j][c] = k[c][j]
    __syncthreads();
    gemm_step(As, Bs, acc, wm, wn, lr, sw);
    __syncthreads();
  }
  const float scale = 0.044194173824159216f;  // 512^-0.5
  int r0 = m0 + wm + ((lane >> 4) << 2);
#pragma unroll
  for (int i = 0; i < 4; ++i)
#pragma unroll
    for (int j = 0; j < 4; ++j){
      int col = n0 + wn + j * 16 + lr;
#pragma unroll
      for (int r = 0; r < 4; ++r){
        int row = r0 + i * 16 + r;
        pb[(size_t)row * Nn + col] = f2b(acc[i][j][r] * scale);
      }
    }
}

// ---------------- row softmax in place over P (2048 wide) ----------------
__global__ __launch_bounds__(256) void k_softmax(u16* __restrict__ p){
  size_t r = blockIdx.x;
  u16* row = p + r * (size_t)Nn;
  int t = threadIdx.x;
  uint4 raw = ((uint4*)row)[t];
  u16* u = (u16*)&raw;
  float vals[8];
  float m = -1e30f;
#pragma unroll
  for (int e = 0; e < 8; ++e){ vals[e] = b2f(u[e]); m = fmaxf(m, vals[e]); }
#pragma unroll
  for (int o = 32; o >= 1; o >>= 1) m = fmaxf(m, __shfl_xor(m, o));
  __shared__ float sm[4], ssum[4];
  int w = t >> 6;
  if ((t & 63) == 0) sm[w] = m;
  __syncthreads();
  m = fmaxf(fmaxf(sm[0], sm[1]), fmaxf(sm[2], sm[3]));
  float s = 0.f;
#pragma unroll
  for (int e = 0; e < 8; ++e){ vals[e] = __expf(vals[e] - m); s += vals[e]; }
#pragma unroll
  for (int o = 32; o >= 1; o >>= 1) s += __shfl_xor(s, o);
  if ((t & 63) == 0) ssum[w] = s;
  __syncthreads();
  s = ssum[0] + ssum[1] + ssum[2] + ssum[3];
  float inv = 1.f / s;
#pragma unroll
  for (int e = 0; e < 8; ++e) u[e] = f2b(vals[e] * inv);
  ((uint4*)row)[t] = raw;
}

// ---------------- attn-out: AO = V * P^T ----------------
__global__ __launch_bounds__(256) void k_pv(const u16* __restrict__ v, const u16* __restrict__ p,
                                            u16* __restrict__ ao){
  __shared__ u16 As[LDS_SZ], Bs[LDS_SZ];
  int b = blockIdx.z;
  const u16* vb = v + (size_t)b * Cc * Nn;
  const u16* pb = p + (size_t)b * Nn * Nn;
  u16* aob = ao + (size_t)b * Cc * Nn;
  int m0 = blockIdx.x * 128, n0 = blockIdx.y * 128;
  GEMM_PROLOGUE
  for (int k0 = 0; k0 < Nn; k0 += 32){
    stage_direct_bf16(As, vb + (size_t)m0 * Nn + k0, Nn);        // As[c][j] = v[c][j]
    stage_direct_bf16(Bs, pb + (size_t)n0 * Nn + k0, Nn);        // Bs[i][j] = P[i][j]
    __syncthreads();
    gemm_step(As, Bs, acc, wm, wn, lr, sw);
    __syncthreads();
  }
  int r0 = m0 + wm + ((lane >> 4) << 2);
#pragma unroll
  for (int i = 0; i < 4; ++i)
#pragma unroll
    for (int j = 0; j < 4; ++j){
      int col = n0 + wn + j * 16 + lr;
#pragma unroll
      for (int r = 0; r < 4; ++r){
        int row = r0 + i * 16 + r;
        aob[(size_t)row * Nn + col] = f2b(acc[i][j][r]);
      }
    }
}

// ---------------- output projection + bias + residual (fp32 out) ----------------
__global__ __launch_bounds__(256) void k_proj(const u16* __restrict__ ao, const float* __restrict__ wo,
                                              const float* __restrict__ bo, const float* __restrict__ x,
                                              float* __restrict__ out){
  __shared__ u16 As[LDS_SZ], Bs[LDS_SZ];
  int b = blockIdx.z;
  const u16* aob = ao + (size_t)b * Cc * Nn;
  int m0 = blockIdx.x * 128, n0 = blockIdx.y * 128;
  GEMM_PROLOGUE
  for (int k0 = 0; k0 < Cc; k0 += 32){
    stage_direct_f32(As, wo + (size_t)m0 * Cc + k0, Cc);
    stage_transpose(Bs, aob + (size_t)k0 * Nn + n0, Nn);
    __syncthreads();
    gemm_step(As, Bs, acc, wm, wn, lr, sw);
    __syncthreads();
  }
  size_t base = (size_t)b * Cc * Nn;
  int r0 = m0 + wm + ((lane >> 4) << 2);
#pragma unroll
  for (int i = 0; i < 4; ++i)
#pragma unroll
    for (int j = 0; j < 4; ++j){
      int col = n0 + wn + j * 16 + lr;
#pragma unroll
      for (int r = 0; r < 4; ++r){
        int row = r0 + i * 16 + r;
        size_t idx = base + (size_t)row * Nn + col;
        out[idx] = x[idx] + bo[row] + acc[i][j][r];
      }
    }
}

extern "C" void kernel_launch(void* const* d_in, const int* in_sizes, int n_in,
                              void* d_out, int out_size, void* d_ws, size_t ws_size,
                              hipStream_t stream){
  const float* x     = (const float*)d_in[0];
  const float* gamma = (const float*)d_in[1];
  const float* beta  = (const float*)d_in[2];
  const float* wq = (const float*)d_in[3];
  const float* bq = (const float*)d_in[4];
  const float* wk = (const float*)d_in[5];
  const float* bk = (const float*)d_in[6];
  const float* wv = (const float*)d_in[7];
  const float* bv = (const float*)d_in[8];
  const float* wo = (const float*)d_in[9];
  const float* bo = (const float*)d_in[10];
  float* out = (float*)d_out;

  char* ws = (char*)d_ws;
  const size_t SZ = 33554432ull;            // 32 MB = b*c*n bf16
  u16* h  = (u16*)(ws);                     // [b,c,n] bf16 (reused as attn-out later)
  u16* q  = (u16*)(ws + 1 * SZ);
  u16* k  = (u16*)(ws + 2 * SZ);
  u16* v  = (u16*)(ws + 3 * SZ);
  u16* p  = (u16*)(ws + 4 * SZ);            // [b,n,n] bf16 = 128 MB
  u16* ao = h;                              // h is dead after k_qkv

  k_gn<<<dim3(512), dim3(256), 0, stream>>>(x, gamma, beta, h);
  k_qkv<<<dim3(4, 16, 48), dim3(256), 0, stream>>>(h, wq, bq, wk, bk, wv, bv, q, k, v);
  k_scores<<<dim3(16, 16, 16), dim3(256), 0, stream>>>(q, k, p);
  k_softmax<<<dim3(32768), dim3(256), 0, stream>>>(p);
  k_pv<<<dim3(4, 16, 16), dim3(256), 0, stream>>>(v, p, ao);
  k_proj<<<dim3(4, 16, 16), dim3(256), 0, stream>>>(ao, wo, bo, x, out);
}

// Round 2
// 433.249 us; speedup vs baseline: 1.1402x; 1.1402x over previous
//
#include <hip/hip_runtime.h>
#include <hip/hip_bf16.h>
#include <math.h>

#define Bb 16
#define Cc 512
#define Nn 2048
#define BK 32

typedef unsigned short u16;
typedef __attribute__((ext_vector_type(8))) short bf16x8;
typedef __attribute__((ext_vector_type(4))) float f32x4;

typedef __attribute__((address_space(3))) unsigned as3_u32;
typedef __attribute__((address_space(1))) const unsigned as1_u32;

__device__ __forceinline__ float b2f(u16 u){ unsigned x = ((unsigned)u) << 16; return __builtin_bit_cast(float, x); }
__device__ __forceinline__ u16 f2b(float f){
  unsigned x = __builtin_bit_cast(unsigned, f);
  x += 0x7fffu + ((x >> 16) & 1u);
  return (u16)(x >> 16);
}

// async global -> LDS, 16B per lane. LDS dest is wave-uniform base + lane*16.
__device__ __forceinline__ void gload16(const u16* g, u16* l){
  __builtin_amdgcn_global_load_lds((as1_u32*)(uintptr_t)(const void*)g,
                                   (as3_u32*)(uintptr_t)(void*)l, 16, 0, 0);
}

// ---------------- weight f32 -> bf16 convert (3 at a time) ----------------
__global__ __launch_bounds__(256) void k_cvt(const float* __restrict__ s0, const float* __restrict__ s1,
                                             const float* __restrict__ s2,
                                             u16* __restrict__ d0, u16* __restrict__ d1, u16* __restrict__ d2){
  const float* s = (blockIdx.z == 0) ? s0 : (blockIdx.z == 1) ? s1 : s2;
  u16* d = (blockIdx.z == 0) ? d0 : (blockIdx.z == 1) ? d1 : d2;
  int i = blockIdx.x * 256 + threadIdx.x;
  float4 v = ((const float4*)s)[i];
  ushort4 o; o.x = f2b(v.x); o.y = f2b(v.y); o.z = f2b(v.z); o.w = f2b(v.w);
  ((ushort4*)d)[i] = o;
}

// ---------------- GroupNorm -> h[c][n] (bf16) ----------------
__global__ __launch_bounds__(256) void k_gn(const float* __restrict__ x,
                                            const float* __restrict__ gamma,
                                            const float* __restrict__ beta,
                                            u16* __restrict__ h){
  int bid = blockIdx.x;
  int b = bid >> 5, g = bid & 31;
  const float4* xv = (const float4*)(x + ((size_t)b * Cc + g * 16) * Nn);
  u16* hp = h + ((size_t)b * Cc + g * 16) * Nn;
  int t = threadIdx.x;
  float s = 0.f, ss = 0.f;
#pragma unroll 4
  for (int it = 0; it < 32; ++it){
    float4 v = xv[it * 256 + t];
    s  += v.x + v.y + v.z + v.w;
    ss += v.x * v.x + v.y * v.y + v.z * v.z + v.w * v.w;
  }
#pragma unroll
  for (int o = 32; o >= 1; o >>= 1){ s += __shfl_xor(s, o); ss += __shfl_xor(ss, o); }
  __shared__ float rs[4], rss[4];
  int w = t >> 6;
  if ((t & 63) == 0){ rs[w] = s; rss[w] = ss; }
  __syncthreads();
  s  = rs[0] + rs[1] + rs[2] + rs[3];
  ss = rss[0] + rss[1] + rss[2] + rss[3];
  float mean = s * (1.f / 32768.f);
  float var  = ss * (1.f / 32768.f) - mean * mean;
  float inv  = rsqrtf(var + 1e-6f);
#pragma unroll 4
  for (int it = 0; it < 32; ++it){
    int idx = it * 256 + t;
    float4 u = xv[idx];
    int ch = g * 16 + (idx >> 9);
    float ga = gamma[ch] * inv, be = beta[ch];
    ushort4 o;
    o.x = f2b((u.x - mean) * ga + be);
    o.y = f2b((u.y - mean) * ga + be);
    o.z = f2b((u.z - mean) * ga + be);
    o.w = f2b((u.w - mean) * ga + be);
    ((ushort4*)hp)[idx] = o;
  }
}

// ---------------- transpose h[c][n] -> h_t[n][c] ----------------
__global__ __launch_bounds__(256) void k_tr(const u16* __restrict__ h, u16* __restrict__ ht){
  __shared__ u16 lds[64 * 65];
  int b = blockIdx.z;
  int n0 = blockIdx.x * 64, c0 = blockIdx.y * 64;
  const u16* src = h + (size_t)b * Cc * Nn;
  u16* dst = ht + (size_t)b * Nn * Cc;
  int t = threadIdx.x;
  int jc = (t & 7) << 3;
  int r  = t >> 3;
#pragma unroll
  for (int it = 0; it < 2; ++it){
    int rr = r + it * 32;      // c-row within tile
    uint4 vv = *(const uint4*)(src + (size_t)(c0 + rr) * Nn + n0 + jc);
    u16* pv = (u16*)&vv;
#pragma unroll
    for (int e = 0; e < 8; ++e) lds[(jc + e) * 65 + rr] = pv[e];   // lds[n_local][c_local]
  }
  __syncthreads();
#pragma unroll
  for (int it = 0; it < 2; ++it){
    int rn = r + it * 32;      // n-row within tile
    u16 tmp[8];
#pragma unroll
    for (int e = 0; e < 8; ++e) tmp[e] = lds[rn * 65 + jc + e];
    *(uint4*)(dst + (size_t)(n0 + rn) * Cc + c0 + jc) = *(const uint4*)tmp;
  }
}

// ---------------- GEMM core: C[128][128] += A[128][K] * B[128][K]^T ----------------
// LDS linear [128][32] per operand; XOR swizzle k^=(row&3)<<3 applied by pre-swizzling
// the per-lane global source address (global_load_lds writes linearly).
__device__ __forceinline__ void gemm_step(const u16* __restrict__ As, const u16* __restrict__ Bs,
                                          f32x4 (&acc)[4][4], int wm, int wn, int lr, int sw){
  bf16x8 af[4], bf[4];
#pragma unroll
  for (int f = 0; f < 4; ++f) af[f] = *(const bf16x8*)&As[(wm + f * 16 + lr) * 32 + sw];
#pragma unroll
  for (int f = 0; f < 4; ++f) bf[f] = *(const bf16x8*)&Bs[(wn + f * 16 + lr) * 32 + sw];
#pragma unroll
  for (int i = 0; i < 4; ++i)
#pragma unroll
    for (int j = 0; j < 4; ++j)
      acc[i][j] = __builtin_amdgcn_mfma_f32_16x16x32_bf16(af[i], bf[j], acc[i][j], 0, 0, 0);
}

#define GEMM_PROLOGUE \
  int lane = threadIdx.x & 63, wid = threadIdx.x >> 6; \
  int wm = (wid >> 1) * 64, wn = (wid & 1) * 64; \
  int lr = lane & 15; \
  int sw = ((lane >> 4) << 3) ^ ((lr & 3) << 3); \
  f32x4 acc[4][4]; \
  { f32x4 z = {0.f, 0.f, 0.f, 0.f}; \
    for (int i = 0; i < 4; ++i) for (int j = 0; j < 4; ++j) acc[i][j] = z; }

__device__ __forceinline__ void gemm_core(const u16* __restrict__ A, int lda,
                                          const u16* __restrict__ B, int ldb, int K,
                                          u16* __restrict__ As, u16* __restrict__ Bs,
                                          f32x4 (&acc)[4][4], int wm, int wn, int lr, int sw){
  int tid = threadIdx.x;
  int w = tid >> 6;
  int kd = (tid & 3) << 3;
  int m0l = tid >> 2;                 // 0..63
  int m1l = m0l + 64;                 // 64..127
  const u16* gA0 = A + (size_t)m0l * lda + (kd ^ ((m0l & 3) << 3));
  const u16* gA1 = A + (size_t)m1l * lda + (kd ^ ((m1l & 3) << 3));
  const u16* gB0 = B + (size_t)m0l * ldb + (kd ^ ((m0l & 3) << 3));
  const u16* gB1 = B + (size_t)m1l * ldb + (kd ^ ((m1l & 3) << 3));
  u16* lA0 = As + (w << 9);           // (w*64)*8 u16
  u16* lA1 = As + 2048 + (w << 9);
  u16* lB0 = Bs + (w << 9);
  u16* lB1 = Bs + 2048 + (w << 9);
  for (int ks = 0; ks < K; ks += BK){
    gload16(gA0 + ks, lA0);
    gload16(gA1 + ks, lA1);
    gload16(gB0 + ks, lB0);
    gload16(gB1 + ks, lB1);
    __syncthreads();                  // drains vmcnt(0): staged data visible
    gemm_step(As, Bs, acc, wm, wn, lr, sw);
    __syncthreads();                  // reads done before next stage overwrites
  }
}

// ---------------- q_t / k_t: [n][co] = h_t[n][c] * w[co][c]^T + b[co] ----------------
__global__ __launch_bounds__(256) void k_qkt(const u16* __restrict__ ht,
                                             const u16* __restrict__ wqb, const u16* __restrict__ wkb,
                                             const float* __restrict__ bq, const float* __restrict__ bk,
                                             u16* __restrict__ qt, u16* __restrict__ kt){
  __shared__ u16 As[4096], Bs[4096];
  int z = blockIdx.z, b = z >> 1, p = z & 1;
  int m0 = blockIdx.x * 128, n0 = blockIdx.y * 128;
  const u16* A = ht + (size_t)b * Nn * Cc + (size_t)m0 * Cc;
  const u16* B = (p ? wkb : wqb) + (size_t)n0 * Cc;
  const float* bias = p ? bk : bq;
  u16* out = (p ? kt : qt) + (size_t)b * Nn * Cc;
  GEMM_PROLOGUE
  gemm_core(A, Cc, B, Cc, Cc, As, Bs, acc, wm, wn, lr, sw);
  int r0 = m0 + wm + ((lane >> 4) << 2);
#pragma unroll
  for (int i = 0; i < 4; ++i)
#pragma unroll
    for (int j = 0; j < 4; ++j){
      int col = n0 + wn + j * 16 + lr;
      float bi = bias[col];
#pragma unroll
      for (int r = 0; r < 4; ++r)
        out[(size_t)(r0 + i * 16 + r) * Cc + col] = f2b(acc[i][j][r] + bi);
    }
}

// ---------------- v: [co][n] = w[co][c] * h_t[n][c]^T + b[co] ----------------
__global__ __launch_bounds__(256) void k_vproj(const u16* __restrict__ wvb, const u16* __restrict__ ht,
                                               const float* __restrict__ bv, u16* __restrict__ v){
  __shared__ u16 As[4096], Bs[4096];
  int b = blockIdx.z;
  int m0 = blockIdx.x * 128, n0 = blockIdx.y * 128;
  const u16* A = wvb + (size_t)m0 * Cc;
  const u16* B = ht + (size_t)b * Nn * Cc + (size_t)n0 * Cc;
  u16* out = v + (size_t)b * Cc * Nn;
  GEMM_PROLOGUE
  gemm_core(A, Cc, B, Cc, Cc, As, Bs, acc, wm, wn, lr, sw);
  int r0 = m0 + wm + ((lane >> 4) << 2);
#pragma unroll
  for (int i = 0; i < 4; ++i)
#pragma unroll
    for (int j = 0; j < 4; ++j){
      int col = n0 + wn + j * 16 + lr;
#pragma unroll
      for (int r = 0; r < 4; ++r){
        int row = r0 + i * 16 + r;
        out[(size_t)row * Nn + col] = f2b(acc[i][j][r] + bv[row]);
      }
    }
}

// ---------------- scores: P[nq][m] = scale * q_t[nq][c] * k_t[m][c]^T ----------------
__global__ __launch_bounds__(256) void k_scores(const u16* __restrict__ qt, const u16* __restrict__ kt,
                                                u16* __restrict__ p){
  __shared__ u16 As[4096], Bs[4096];
  int b = blockIdx.z;
  int m0 = blockIdx.x * 128, n0 = blockIdx.y * 128;
  const u16* A = qt + (size_t)b * Nn * Cc + (size_t)m0 * Cc;
  const u16* B = kt + (size_t)b * Nn * Cc + (size_t)n0 * Cc;
  u16* pb = p + (size_t)b * Nn * Nn;
  GEMM_PROLOGUE
  gemm_core(A, Cc, B, Cc, Cc, As, Bs, acc, wm, wn, lr, sw);
  const float scale = 0.044194173824159216f;
  int r0 = m0 + wm + ((lane >> 4) << 2);
#pragma unroll
  for (int i = 0; i < 4; ++i)
#pragma unroll
    for (int j = 0; j < 4; ++j){
      int col = n0 + wn + j * 16 + lr;
#pragma unroll
      for (int r = 0; r < 4; ++r)
        pb[(size_t)(r0 + i * 16 + r) * Nn + col] = f2b(acc[i][j][r] * scale);
    }
}

// ---------------- row softmax in place over P ----------------
__global__ __launch_bounds__(256) void k_softmax(u16* __restrict__ p){
  size_t r = blockIdx.x;
  u16* row = p + r * (size_t)Nn;
  int t = threadIdx.x;
  uint4 raw = ((uint4*)row)[t];
  u16* u = (u16*)&raw;
  float vals[8];
  float m = -1e30f;
#pragma unroll
  for (int e = 0; e < 8; ++e){ vals[e] = b2f(u[e]); m = fmaxf(m, vals[e]); }
#pragma unroll
  for (int o = 32; o >= 1; o >>= 1) m = fmaxf(m, __shfl_xor(m, o));
  __shared__ float sm[4], ssum[4];
  int w = t >> 6;
  if ((t & 63) == 0) sm[w] = m;
  __syncthreads();
  m = fmaxf(fmaxf(sm[0], sm[1]), fmaxf(sm[2], sm[3]));
  float s = 0.f;
#pragma unroll
  for (int e = 0; e < 8; ++e){ vals[e] = __expf(vals[e] - m); s += vals[e]; }
#pragma unroll
  for (int o = 32; o >= 1; o >>= 1) s += __shfl_xor(s, o);
  if ((t & 63) == 0) ssum[w] = s;
  __syncthreads();
  s = ssum[0] + ssum[1] + ssum[2] + ssum[3];
  float inv = 1.f / s;
#pragma unroll
  for (int e = 0; e < 8; ++e) u[e] = f2b(vals[e] * inv);
  ((uint4*)row)[t] = raw;
}

// ---------------- PV: ao_t[nq][c] = P[nq][m] * v[c][m]^T ----------------
__global__ __launch_bounds__(256) void k_pv(const u16* __restrict__ p, const u16* __restrict__ v,
                                            u16* __restrict__ aot){
  __shared__ u16 As[4096], Bs[4096];
  int b = blockIdx.z;
  int m0 = blockIdx.x * 128, n0 = blockIdx.y * 128;
  const u16* A = p + (size_t)b * Nn * Nn + (size_t)m0 * Nn;
  const u16* B = v + (size_t)b * Cc * Nn + (size_t)n0 * Nn;
  u16* out = aot + (size_t)b * Nn * Cc;
  GEMM_PROLOGUE
  gemm_core(A, Nn, B, Nn, Nn, As, Bs, acc, wm, wn, lr, sw);
  int r0 = m0 + wm + ((lane >> 4) << 2);
#pragma unroll
  for (int i = 0; i < 4; ++i)
#pragma unroll
    for (int j = 0; j < 4; ++j){
      int col = n0 + wn + j * 16 + lr;
#pragma unroll
      for (int r = 0; r < 4; ++r)
        out[(size_t)(r0 + i * 16 + r) * Cc + col] = f2b(acc[i][j][r]);
    }
}

// ---------------- proj + residual: out[co][n] = x + bo[co] + wo[co][c]*ao_t[n][c]^T ----------------
__global__ __launch_bounds__(256) void k_proj(const u16* __restrict__ wob, const u16* __restrict__ aot,
                                              const float* __restrict__ bo, const float* __restrict__ x,
                                              float* __restrict__ out){
  __shared__ u16 As[4096], Bs[4096];
  int b = blockIdx.z;
  int m0 = blockIdx.x * 128, n0 = blockIdx.y * 128;
  const u16* A = wob + (size_t)m0 * Cc;
  const u16* B = aot + (size_t)b * Nn * Cc + (size_t)n0 * Cc;
  GEMM_PROLOGUE
  gemm_core(A, Cc, B, Cc, Cc, As, Bs, acc, wm, wn, lr, sw);
  size_t base = (size_t)b * Cc * Nn;
  int r0 = m0 + wm + ((lane >> 4) << 2);
#pragma unroll
  for (int i = 0; i < 4; ++i)
#pragma unroll
    for (int j = 0; j < 4; ++j){
      int col = n0 + wn + j * 16 + lr;
#pragma unroll
      for (int r = 0; r < 4; ++r){
        int row = r0 + i * 16 + r;
        size_t idx = base + (size_t)row * Nn + col;
        out[idx] = x[idx] + bo[row] + acc[i][j][r];
      }
    }
}

extern "C" void kernel_launch(void* const* d_in, const int* in_sizes, int n_in,
                              void* d_out, int out_size, void* d_ws, size_t ws_size,
                              hipStream_t stream){
  const float* x     = (const float*)d_in[0];
  const float* gamma = (const float*)d_in[1];
  const float* beta  = (const float*)d_in[2];
  const float* wq = (const float*)d_in[3];
  const float* bq = (const float*)d_in[4];
  const float* wk = (const float*)d_in[5];
  const float* bk = (const float*)d_in[6];
  const float* wv = (const float*)d_in[7];
  const float* bv = (const float*)d_in[8];
  const float* wo = (const float*)d_in[9];
  const float* bo = (const float*)d_in[10];
  float* out = (float*)d_out;

  char* ws = (char*)d_ws;
  const size_t MB = 1048576ull;
  u16* ht  = (u16*)(ws);             // 32MB: h_t[n][c]; reused as ao_t after qkv
  u16* qt  = (u16*)(ws + 32 * MB);   // 32MB: q_t; head reused as wo_bf after scores
  u16* kt  = (u16*)(ws + 64 * MB);   // 32MB
  u16* v   = (u16*)(ws + 96 * MB);   // 32MB: v[c][n]
  u16* P   = (u16*)(ws + 128 * MB);  // 128MB: scores/softmax
  // transients inside the P region (dead before k_scores writes P):
  u16* wqb = P;                      // 0.5MB each
  u16* wkb = P + 262144;
  u16* wvb = P + 524288;
  u16* h   = (u16*)(ws + 130 * MB);  // 32MB: h[c][n]
  u16* wob = qt;                     // after k_scores, q_t is dead
  u16* aot = ht;                     // after qkv/v, h_t is dead

  k_cvt<<<dim3(256, 1, 3), 256, 0, stream>>>(wq, wk, wv, wqb, wkb, wvb);
  k_gn<<<dim3(512), 256, 0, stream>>>(x, gamma, beta, h);
  k_tr<<<dim3(32, 8, 16), 256, 0, stream>>>(h, ht);
  k_qkt<<<dim3(16, 4, 32), 256, 0, stream>>>(ht, wqb, wkb, bq, bk, qt, kt);
  k_vproj<<<dim3(4, 16, 16), 256, 0, stream>>>(wvb, ht, bv, v);
  k_scores<<<dim3(16, 16, 16), 256, 0, stream>>>(qt, kt, P);
  k_cvt<<<dim3(256, 1, 1), 256, 0, stream>>>(wo, wo, wo, wob, wob, wob);
  k_softmax<<<dim3(32768), 256, 0, stream>>>(P);
  k_pv<<<dim3(16, 4, 16), 256, 0, stream>>>(P, v, aot);
  k_proj<<<dim3(4, 16, 16), 256, 0, stream>>>(wob, aot, bo, x, out);
}

// Round 3
// 365.628 us; speedup vs baseline: 1.3511x; 1.1849x over previous
//
#include <hip/hip_runtime.h>
#include <hip/hip_bf16.h>
#include <math.h>

#define Bb 16
#define Cc 512
#define Nn 2048

typedef unsigned short u16;
typedef __attribute__((ext_vector_type(8))) short bf16x8;
typedef __attribute__((ext_vector_type(4))) float f32x4;

typedef __attribute__((address_space(3))) unsigned as3_u32;
typedef __attribute__((address_space(1))) const unsigned as1_u32;

__device__ __forceinline__ float b2f(u16 u){ unsigned x = ((unsigned)u) << 16; return __builtin_bit_cast(float, x); }
__device__ __forceinline__ u16 f2b(float f){
  unsigned x = __builtin_bit_cast(unsigned, f);
  x += 0x7fffu + ((x >> 16) & 1u);
  return (u16)(x >> 16);
}

// async global -> LDS, 16B per lane; LDS dest is wave-uniform base + lane*16.
__device__ __forceinline__ void gload16(const u16* g, u16* l){
  __builtin_amdgcn_global_load_lds((as1_u32*)(uintptr_t)(const void*)g,
                                   (as3_u32*)(uintptr_t)(void*)l, 16, 0, 0);
}

#define BAR() do{ __builtin_amdgcn_s_barrier(); asm volatile("" ::: "memory"); }while(0)
#define WAITV4() asm volatile("s_waitcnt vmcnt(4)" ::: "memory")
#define WAITV0() asm volatile("s_waitcnt vmcnt(0)" ::: "memory")

// ---------------- weight f32 -> bf16 convert ----------------
__global__ __launch_bounds__(256) void k_cvt(const float* __restrict__ s0, const float* __restrict__ s1,
                                             const float* __restrict__ s2,
                                             u16* __restrict__ d0, u16* __restrict__ d1, u16* __restrict__ d2){
  const float* s = (blockIdx.z == 0) ? s0 : (blockIdx.z == 1) ? s1 : s2;
  u16* d = (blockIdx.z == 0) ? d0 : (blockIdx.z == 1) ? d1 : d2;
  int i = blockIdx.x * 256 + threadIdx.x;
  float4 v = ((const float4*)s)[i];
  ushort4 o; o.x = f2b(v.x); o.y = f2b(v.y); o.z = f2b(v.z); o.w = f2b(v.w);
  ((ushort4*)d)[i] = o;
}

// ---------------- GroupNorm -> h[c][n] (bf16) ----------------
__global__ __launch_bounds__(256) void k_gn(const float* __restrict__ x,
                                            const float* __restrict__ gamma,
                                            const float* __restrict__ beta,
                                            u16* __restrict__ h){
  int bid = blockIdx.x;
  int b = bid >> 5, g = bid & 31;
  const float4* xv = (const float4*)(x + ((size_t)b * Cc + g * 16) * Nn);
  u16* hp = h + ((size_t)b * Cc + g * 16) * Nn;
  int t = threadIdx.x;
  float s = 0.f, ss = 0.f;
#pragma unroll 4
  for (int it = 0; it < 32; ++it){
    float4 v = xv[it * 256 + t];
    s  += v.x + v.y + v.z + v.w;
    ss += v.x * v.x + v.y * v.y + v.z * v.z + v.w * v.w;
  }
#pragma unroll
  for (int o = 32; o >= 1; o >>= 1){ s += __shfl_xor(s, o); ss += __shfl_xor(ss, o); }
  __shared__ float rs[4], rss[4];
  int w = t >> 6;
  if ((t & 63) == 0){ rs[w] = s; rss[w] = ss; }
  __syncthreads();
  s  = rs[0] + rs[1] + rs[2] + rs[3];
  ss = rss[0] + rss[1] + rss[2] + rss[3];
  float mean = s * (1.f / 32768.f);
  float var  = ss * (1.f / 32768.f) - mean * mean;
  float inv  = rsqrtf(var + 1e-6f);
#pragma unroll 4
  for (int it = 0; it < 32; ++it){
    int idx = it * 256 + t;
    float4 u = xv[idx];
    int ch = g * 16 + (idx >> 9);
    float ga = gamma[ch] * inv, be = beta[ch];
    ushort4 o;
    o.x = f2b((u.x - mean) * ga + be);
    o.y = f2b((u.y - mean) * ga + be);
    o.z = f2b((u.z - mean) * ga + be);
    o.w = f2b((u.w - mean) * ga + be);
    ((ushort4*)hp)[idx] = o;
  }
}

// ---------------- transpose h[c][n] -> h_t[n][c] ----------------
__global__ __launch_bounds__(256) void k_tr(const u16* __restrict__ h, u16* __restrict__ ht){
  __shared__ u16 lds[64 * 65];
  int b = blockIdx.z;
  int n0 = blockIdx.x * 64, c0 = blockIdx.y * 64;
  const u16* src = h + (size_t)b * Cc * Nn;
  u16* dst = ht + (size_t)b * Nn * Cc;
  int t = threadIdx.x;
  int jc = (t & 7) << 3;
  int r  = t >> 3;
#pragma unroll
  for (int it = 0; it < 2; ++it){
    int rr = r + it * 32;
    uint4 vv = *(const uint4*)(src + (size_t)(c0 + rr) * Nn + n0 + jc);
    u16* pv = (u16*)&vv;
#pragma unroll
    for (int e = 0; e < 8; ++e) lds[(jc + e) * 65 + rr] = pv[e];
  }
  __syncthreads();
#pragma unroll
  for (int it = 0; it < 2; ++it){
    int rn = r + it * 32;
    u16 tmp[8];
#pragma unroll
    for (int e = 0; e < 8; ++e) tmp[e] = lds[rn * 65 + jc + e];
    *(uint4*)(dst + (size_t)(n0 + rn) * Cc + c0 + jc) = *(const uint4*)tmp;
  }
}

// =====================================================================
// 256x256 / BK=32 / 8-wave / 3-slot counted-vmcnt GEMM core.
// C[256][256] = A[256 rows][K] * B[256 rows][K]^T  (both operands [row][k])
// LDS: 3 slots x (A[256][32] + B[256][32]) bf16 = 96 KB.
// XOR swizzle: 16B-chunk' = chunk ^ ((row>>1)&3), applied on the global
// source address (linear gload_lds dest) and on the ds_read side.
// Steady state: stage tile T+2 during tile T's 2 phases; s_waitcnt vmcnt(4)
// once per tile (waits next tile's 4 loads, keeps 4 in flight).
// =====================================================================
#define SLOT_U16 16384

__device__ __forceinline__ void gemm256(const u16* __restrict__ A, int lda,
                                        const u16* __restrict__ B, int ldb, int K,
                                        u16* __restrict__ lds, f32x4 (&acc)[8][4]){
  const int tid = threadIdx.x;
  const int w = tid >> 6, lane = tid & 63;
  const int lr = lane & 15, lk = lane >> 4;
  const int wr = w >> 2, wc = w & 3;

  // fragment read offsets (u16 units; row stride = 32 u16 = 64 B)
  const int swzc = lk ^ ((lr >> 1) & 3);
  const int aoff = (wr * 128 + lr) * 32 + 8 * swzc;
  const int boff = 8192 + (wc * 64 + lr) * 32 + 8 * swzc;

  // staging: thread covers block-linear lane-slots idx0, idx1 (0..1023)
  const int idx0 = w * 128 + lane;
  const int idx1 = idx0 + 64;
  const int r0s = idx0 >> 2, r1s = idx1 >> 2;
  const int c0 = (idx0 & 3) ^ ((r0s >> 1) & 3);
  const int c1 = (idx1 & 3) ^ ((r1s >> 1) & 3);
  const u16* gA0 = A + (size_t)r0s * lda + 8 * c0;
  const u16* gA1 = A + (size_t)r1s * lda + 8 * c1;
  const u16* gB0 = B + (size_t)r0s * ldb + 8 * c0;
  const u16* gB1 = B + (size_t)r1s * ldb + 8 * c1;
  const int dst0 = w * 1024;        // (w*128)*8 u16
  const int dst1 = dst0 + 512;

#pragma unroll
  for (int i = 0; i < 8; ++i)
#pragma unroll
    for (int j = 0; j < 4; ++j){ f32x4 z = {0.f,0.f,0.f,0.f}; acc[i][j] = z; }

  const int NT = K >> 5;

  // prologue: stage tiles 0 and 1
  gload16(gA0,      lds + dst0);            gload16(gA1,      lds + dst1);
  gload16(gB0,      lds + 8192 + dst0);     gload16(gB1,      lds + 8192 + dst1);
  gload16(gA0 + 32, lds + SLOT_U16 + dst0); gload16(gA1 + 32, lds + SLOT_U16 + dst1);
  gload16(gB0 + 32, lds + SLOT_U16 + 8192 + dst0);
  gload16(gB1 + 32, lds + SLOT_U16 + 8192 + dst1);
  WAITV4();
  BAR();

  int s = 0;
#pragma unroll 1
  for (int T = 0; T < NT; ++T){
    const u16* Asl = lds + s * SLOT_U16;
    int st = s + 2; if (st >= 3) st -= 3;
    u16* stl = lds + st * SLOT_U16;
    const bool pf = (T + 2) < NT;
    const int kk = (T + 2) << 5;

    // ---- phase 0 ----
    bf16x8 a0[4], b0[4];
#pragma unroll
    for (int i = 0; i < 4; ++i) a0[i] = *(const bf16x8*)(Asl + aoff + i * 512);
#pragma unroll
    for (int j = 0; j < 4; ++j) b0[j] = *(const bf16x8*)(Asl + boff + j * 512);
    if (pf){ gload16(gA0 + kk, stl + dst0); gload16(gA1 + kk, stl + dst1); }
    BAR();
    __builtin_amdgcn_s_setprio(1);
#pragma unroll
    for (int i = 0; i < 4; ++i)
#pragma unroll
      for (int j = 0; j < 4; ++j)
        acc[i][j] = __builtin_amdgcn_mfma_f32_16x16x32_bf16(a0[i], b0[j], acc[i][j], 0, 0, 0);
    __builtin_amdgcn_s_setprio(0);
    BAR();

    // ---- phase 1 ----
    bf16x8 a1[4];
#pragma unroll
    for (int i = 0; i < 4; ++i) a1[i] = *(const bf16x8*)(Asl + aoff + (i + 4) * 512);
    if (pf){ gload16(gB0 + kk, stl + 8192 + dst0); gload16(gB1 + kk, stl + 8192 + dst1); }
    BAR();
    __builtin_amdgcn_s_setprio(1);
#pragma unroll
    for (int i = 0; i < 4; ++i)
#pragma unroll
      for (int j = 0; j < 4; ++j)
        acc[i + 4][j] = __builtin_amdgcn_mfma_f32_16x16x32_bf16(a1[i], b0[j], acc[i + 4][j], 0, 0, 0);
    __builtin_amdgcn_s_setprio(0);
    if (pf){ WAITV4(); } else { WAITV0(); }
    BAR();
    s = (s + 1 == 3) ? 0 : s + 1;
  }
}

#define EPI_COORDS \
  int lane = threadIdx.x & 63, w = threadIdx.x >> 6; \
  int wr = w >> 2, wc = w & 3; \
  int lr = lane & 15; \
  int r0 = (lane >> 4) << 2;

// ---------------- q_t / k_t: [n][co] ----------------
__global__ __launch_bounds__(512, 2) void k_qkt(const u16* __restrict__ ht,
                                                const u16* __restrict__ wqb, const u16* __restrict__ wkb,
                                                const float* __restrict__ bq, const float* __restrict__ bk,
                                                u16* __restrict__ qt, u16* __restrict__ kt){
  __shared__ u16 lds[3 * SLOT_U16];
  int z = blockIdx.z, b = z >> 1, p = z & 1;
  int m0 = blockIdx.x * 256, n0 = blockIdx.y * 256;
  const u16* A = ht + (size_t)b * Nn * Cc + (size_t)m0 * Cc;
  const u16* B = (p ? wkb : wqb) + (size_t)n0 * Cc;
  const float* bias = p ? bk : bq;
  u16* out = (p ? kt : qt) + (size_t)b * Nn * Cc;
  f32x4 acc[8][4];
  gemm256(A, Cc, B, Cc, Cc, lds, acc);
  EPI_COORDS
#pragma unroll
  for (int i = 0; i < 8; ++i)
#pragma unroll
    for (int j = 0; j < 4; ++j){
      int col = n0 + wc * 64 + j * 16 + lr;
      float bi = bias[col];
      int row = m0 + wr * 128 + i * 16 + r0;
#pragma unroll
      for (int r = 0; r < 4; ++r)
        out[(size_t)(row + r) * Cc + col] = f2b(acc[i][j][r] + bi);
    }
}

// ---------------- v: [co][n] ----------------
__global__ __launch_bounds__(512, 2) void k_vproj(const u16* __restrict__ wvb, const u16* __restrict__ ht,
                                                  const float* __restrict__ bv, u16* __restrict__ v){
  __shared__ u16 lds[3 * SLOT_U16];
  int b = blockIdx.z;
  int m0 = blockIdx.x * 256, n0 = blockIdx.y * 256;
  const u16* A = wvb + (size_t)m0 * Cc;
  const u16* B = ht + (size_t)b * Nn * Cc + (size_t)n0 * Cc;
  u16* out = v + (size_t)b * Cc * Nn;
  f32x4 acc[8][4];
  gemm256(A, Cc, B, Cc, Cc, lds, acc);
  EPI_COORDS
#pragma unroll
  for (int i = 0; i < 8; ++i)
#pragma unroll
    for (int j = 0; j < 4; ++j){
      int col = n0 + wc * 64 + j * 16 + lr;
      int row = m0 + wr * 128 + i * 16 + r0;
#pragma unroll
      for (int r = 0; r < 4; ++r)
        out[(size_t)(row + r) * Nn + col] = f2b(acc[i][j][r] + bv[row + r]);
    }
}

// ---------------- scores: P[nq][m] = scale * q_t k_t^T ----------------
__global__ __launch_bounds__(512, 2) void k_scores(const u16* __restrict__ qt, const u16* __restrict__ kt,
                                                   u16* __restrict__ p){
  __shared__ u16 lds[3 * SLOT_U16];
  int b = blockIdx.z;
  int m0 = blockIdx.x * 256, n0 = blockIdx.y * 256;
  const u16* A = qt + (size_t)b * Nn * Cc + (size_t)m0 * Cc;
  const u16* B = kt + (size_t)b * Nn * Cc + (size_t)n0 * Cc;
  u16* pb = p + (size_t)b * Nn * Nn;
  f32x4 acc[8][4];
  gemm256(A, Cc, B, Cc, Cc, lds, acc);
  const float scale = 0.044194173824159216f;
  EPI_COORDS
#pragma unroll
  for (int i = 0; i < 8; ++i)
#pragma unroll
    for (int j = 0; j < 4; ++j){
      int col = n0 + wc * 64 + j * 16 + lr;
      int row = m0 + wr * 128 + i * 16 + r0;
#pragma unroll
      for (int r = 0; r < 4; ++r)
        pb[(size_t)(row + r) * Nn + col] = f2b(acc[i][j][r] * scale);
    }
}

// ---------------- row softmax in place over P ----------------
__global__ __launch_bounds__(256) void k_softmax(u16* __restrict__ p){
  size_t r = blockIdx.x;
  u16* row = p + r * (size_t)Nn;
  int t = threadIdx.x;
  uint4 raw = ((uint4*)row)[t];
  u16* u = (u16*)&raw;
  float vals[8];
  float m = -1e30f;
#pragma unroll
  for (int e = 0; e < 8; ++e){ vals[e] = b2f(u[e]); m = fmaxf(m, vals[e]); }
#pragma unroll
  for (int o = 32; o >= 1; o >>= 1) m = fmaxf(m, __shfl_xor(m, o));
  __shared__ float sm[4], ssum[4];
  int w = t >> 6;
  if ((t & 63) == 0) sm[w] = m;
  __syncthreads();
  m = fmaxf(fmaxf(sm[0], sm[1]), fmaxf(sm[2], sm[3]));
  float s = 0.f;
#pragma unroll
  for (int e = 0; e < 8; ++e){ vals[e] = __expf(vals[e] - m); s += vals[e]; }
#pragma unroll
  for (int o = 32; o >= 1; o >>= 1) s += __shfl_xor(s, o);
  if ((t & 63) == 0) ssum[w] = s;
  __syncthreads();
  s = ssum[0] + ssum[1] + ssum[2] + ssum[3];
  float inv = 1.f / s;
#pragma unroll
  for (int e = 0; e < 8; ++e) u[e] = f2b(vals[e] * inv);
  ((uint4*)row)[t] = raw;
}

// ---------------- PV: ao_t[nq][c] = P[nq][m] * v[c][m]^T ----------------
__global__ __launch_bounds__(512, 2) void k_pv(const u16* __restrict__ p, const u16* __restrict__ v,
                                               u16* __restrict__ aot){
  __shared__ u16 lds[3 * SLOT_U16];
  int b = blockIdx.z;
  int m0 = blockIdx.x * 256, n0 = blockIdx.y * 256;
  const u16* A = p + (size_t)b * Nn * Nn + (size_t)m0 * Nn;
  const u16* B = v + (size_t)b * Cc * Nn + (size_t)n0 * Nn;
  u16* out = aot + (size_t)b * Nn * Cc;
  f32x4 acc[8][4];
  gemm256(A, Nn, B, Nn, Nn, lds, acc);
  EPI_COORDS
#pragma unroll
  for (int i = 0; i < 8; ++i)
#pragma unroll
    for (int j = 0; j < 4; ++j){
      int col = n0 + wc * 64 + j * 16 + lr;
      int row = m0 + wr * 128 + i * 16 + r0;
#pragma unroll
      for (int r = 0; r < 4; ++r)
        out[(size_t)(row + r) * Cc + col] = f2b(acc[i][j][r]);
    }
}

// ---------------- proj + residual (fp32 out) ----------------
__global__ __launch_bounds__(512, 2) void k_proj(const u16* __restrict__ wob, const u16* __restrict__ aot,
                                                 const float* __restrict__ bo, const float* __restrict__ x,
                                                 float* __restrict__ out){
  __shared__ u16 lds[3 * SLOT_U16];
  int b = blockIdx.z;
  int m0 = blockIdx.x * 256, n0 = blockIdx.y * 256;
  const u16* A = wob + (size_t)m0 * Cc;
  const u16* B = aot + (size_t)b * Nn * Cc + (size_t)n0 * Cc;
  f32x4 acc[8][4];
  gemm256(A, Cc, B, Cc, Cc, lds, acc);
  size_t base = (size_t)b * Cc * Nn;
  EPI_COORDS
#pragma unroll
  for (int i = 0; i < 8; ++i)
#pragma unroll
    for (int j = 0; j < 4; ++j){
      int col = n0 + wc * 64 + j * 16 + lr;
      int row = m0 + wr * 128 + i * 16 + r0;
#pragma unroll
      for (int r = 0; r < 4; ++r){
        size_t idx = base + (size_t)(row + r) * Nn + col;
        out[idx] = x[idx] + bo[row + r] + acc[i][j][r];
      }
    }
}

extern "C" void kernel_launch(void* const* d_in, const int* in_sizes, int n_in,
                              void* d_out, int out_size, void* d_ws, size_t ws_size,
                              hipStream_t stream){
  const float* x     = (const float*)d_in[0];
  const float* gamma = (const float*)d_in[1];
  const float* beta  = (const float*)d_in[2];
  const float* wq = (const float*)d_in[3];
  const float* bq = (const float*)d_in[4];
  const float* wk = (const float*)d_in[5];
  const float* bk = (const float*)d_in[6];
  const float* wv = (const float*)d_in[7];
  const float* bv = (const float*)d_in[8];
  const float* wo = (const float*)d_in[9];
  const float* bo = (const float*)d_in[10];
  float* out = (float*)d_out;

  char* ws = (char*)d_ws;
  const size_t MB = 1048576ull;
  u16* ht  = (u16*)(ws);             // 32MB: h_t[n][c]; reused as ao_t later
  u16* qt  = (u16*)(ws + 32 * MB);   // 32MB; reused as wo_bf after scores
  u16* kt  = (u16*)(ws + 64 * MB);   // 32MB
  u16* v   = (u16*)(ws + 96 * MB);   // 32MB: v[c][n]
  u16* P   = (u16*)(ws + 128 * MB);  // 128MB
  u16* wqb = P;                      // transients (dead before P written)
  u16* wkb = P + 262144;
  u16* wvb = P + 524288;
  u16* h   = (u16*)(ws + 130 * MB);  // 32MB: h[c][n]
  u16* wob = qt;
  u16* aot = ht;

  k_cvt<<<dim3(256, 1, 3), 256, 0, stream>>>(wq, wk, wv, wqb, wkb, wvb);
  k_gn<<<dim3(512), 256, 0, stream>>>(x, gamma, beta, h);
  k_tr<<<dim3(32, 8, 16), 256, 0, stream>>>(h, ht);
  k_qkt<<<dim3(8, 2, 32), 512, 0, stream>>>(ht, wqb, wkb, bq, bk, qt, kt);
  k_vproj<<<dim3(2, 8, 16), 512, 0, stream>>>(wvb, ht, bv, v);
  k_scores<<<dim3(8, 8, 16), 512, 0, stream>>>(qt, kt, P);
  k_cvt<<<dim3(256, 1, 1), 256, 0, stream>>>(wo, wo, wo, wob, wob, wob);
  k_softmax<<<dim3(32768), 256, 0, stream>>>(P);
  k_pv<<<dim3(8, 2, 16), 512, 0, stream>>>(P, v, aot);
  k_proj<<<dim3(2, 8, 16), 512, 0, stream>>>(wob, aot, bo, x, out);
}